// Round 1
// baseline (74.454 us; speedup 1.0000x reference)
//
#include <hip/hip_runtime.h>
#include <hip/hip_bf16.h>

#define QLEN   1024
#define MLEN   1024
#define KLEN   2048
#define BATCH  8
#define DMODEL 1024
#define NCOLS  (BATCH * DMODEL)   // 8192
#define FTLEN  1025

typedef __attribute__((ext_vector_type(4))) float f32x4;
typedef __attribute__((ext_vector_type(8))) short bf16x8;

typedef __attribute__((address_space(1))) const unsigned int as1_u32;
typedef __attribute__((address_space(3))) unsigned int as3_u32;

static __device__ __forceinline__ unsigned short f2bf(float f) {
    unsigned int u = __builtin_bit_cast(unsigned int, f);
    return (unsigned short)((u + 0x7fffu + ((u >> 16) & 1u)) >> 16);
}

// ---------------------------------------------------------------------------
// Kernel 1: cat = concat(mems, dec) (+ pos_emb), cast bf16, store TRANSPOSED:
// catT[n][k], n = b*1024 + d (8192 rows), k = l (2048 cols, contiguous).
// Grid: (32 l-tiles, 16 d-tiles, 8 b). 64x64 tile via LDS.
// ---------------------------------------------------------------------------
__global__ __launch_bounds__(256) void prep_transpose(
    const float* __restrict__ dec, const float* __restrict__ pos,
    const float* __restrict__ mems, const int* __restrict__ addp,
    unsigned short* __restrict__ catT)
{
    __shared__ unsigned short T[64][72];   // [d_local][l_local], 144B rows (16B aligned)
    const int lt = blockIdx.x, dt = blockIdx.y, b = blockIdx.z;
    const int tid = threadIdx.x;
    const int add_position = addp[0];
    const int l0 = lt * 64, d0 = dt * 64;

    const int lrow = tid >> 4;         // 0..15
    const int dcol = (tid & 15) * 4;   // 0..60
    for (int p = 0; p < 4; ++p) {
        const int ll = p * 16 + lrow;  // 0..63
        const int l = l0 + ll;
        const int d = d0 + dcol;
        const float* src = (l < MLEN)
            ? (mems + (size_t)l * NCOLS + b * DMODEL + d)
            : (dec + (size_t)(l - MLEN) * NCOLS + b * DMODEL + d);
        float4 v = *reinterpret_cast<const float4*>(src);
        if (add_position) {
            float4 pv = *reinterpret_cast<const float4*>(pos + (size_t)l * DMODEL + d);
            v.x += pv.x; v.y += pv.y; v.z += pv.z; v.w += pv.w;
        }
        T[dcol + 0][ll] = f2bf(v.x);
        T[dcol + 1][ll] = f2bf(v.y);
        T[dcol + 2][ll] = f2bf(v.z);
        T[dcol + 3][ll] = f2bf(v.w);
    }
    __syncthreads();
    // store: 64 rows (n) x 64 bf16 (k): 512 chunks of 16B, 2 passes
    for (int p = 0; p < 2; ++p) {
        const int idx = p * 256 + tid;
        const int r = idx >> 3;          // d_local 0..63
        const int c = (idx & 7) * 8;     // l_local
        int4 v = *reinterpret_cast<const int4*>(&T[r][c]);
        size_t n = (size_t)(b * DMODEL + d0 + r);
        *reinterpret_cast<int4*>(&catT[n * KLEN + l0 + c]) = v;
    }
}

// ---------------------------------------------------------------------------
// Kernel 2: W[m][k] bf16, W[m][m+t] = cos(2*pi*(m*t mod 1025)/1025)/sqrt(1025)
// for t in [0,1024], else 0.
// ---------------------------------------------------------------------------
__global__ __launch_bounds__(256) void fill_w(unsigned short* __restrict__ W)
{
    const int idx = blockIdx.x * 256 + threadIdx.x;   // 524288 total, 4 elems each
    const int m = idx >> 9;              // / 512
    const int k4 = (idx & 511) * 4;
    union { unsigned short s[4]; int2 v; } u;
    for (int j = 0; j < 4; ++j) {
        const int k = k4 + j;
        const int t = k - m;
        float w = 0.0f;
        if (t >= 0 && t < FTLEN) {
            const int r = (m * t) % FTLEN;   // < 2^20, int ok
            const float theta = (6.283185307179586f / (float)FTLEN) * (float)r;
            w = cosf(theta) * 0.03123475237772121f;   // 1/sqrt(1025)
        }
        u.s[j] = f2bf(w);
    }
    *reinterpret_cast<int2*>(&W[(size_t)m * KLEN + k4]) = u.v;
}

// ---------------------------------------------------------------------------
// Kernel 3: banded GEMM  x[m][n] = dec[m][n] + (1/sqrt(2048)) * sum_k W[m][k]*catT[n][k]
// 128x128 tile, BK=64, 4 waves (2x2), 16x16x32 bf16 MFMA, global_load_lds w=16.
// K-loop: k0 = m0 + t*64, t = 0..17 (band covers [m0, m0+1152)).
// ---------------------------------------------------------------------------
__global__ __launch_bounds__(256) void gemm_band(
    const unsigned short* __restrict__ W,     // [1024][2048]
    const unsigned short* __restrict__ catT,  // [8192][2048]
    const float* __restrict__ dec,            // [1024][8192]
    float* __restrict__ xout)                 // [1024][8192]
{
    __shared__ unsigned short Alds[128 * 64];
    __shared__ unsigned short Blds[128 * 64];
    const int tid = threadIdx.x;
    const int wave = tid >> 6, lane = tid & 63;
    const int m0 = blockIdx.x * 128;   // 8 blocks
    const int n0 = blockIdx.y * 128;   // 64 blocks
    const int wm = wave >> 1, wn = wave & 1;

    f32x4 acc[4][4];
    for (int i = 0; i < 4; ++i)
        for (int j = 0; j < 4; ++j)
            acc[i][j] = (f32x4){0.f, 0.f, 0.f, 0.f};

    const int srow = lane >> 3;          // 0..7
    const int scol = (lane & 7) * 8;     // element col in tile
    const int fr = lane & 15;
    const int kg = lane >> 4;

    for (int t = 0; t < 18; ++t) {
        const int k0 = m0 + t * 64;
        // stage A (W) and B (catT): each wave 4 calls x 1KB each per tile
        for (int i = 0; i < 4; ++i) {
            const int row = (i * 4 + wave) * 8 + srow;   // 0..127
            __builtin_amdgcn_global_load_lds(
                (as1_u32*)(const void*)(W + (size_t)(m0 + row) * KLEN + k0 + scol),
                (as3_u32*)(void*)(Alds + row * 64 + scol), 16, 0, 0);
            __builtin_amdgcn_global_load_lds(
                (as1_u32*)(const void*)(catT + (size_t)(n0 + row) * KLEN + k0 + scol),
                (as3_u32*)(void*)(Blds + row * 64 + scol), 16, 0, 0);
        }
        __syncthreads();   // drains vmcnt+lgkm, barrier

        for (int ks = 0; ks < 2; ++ks) {
            bf16x8 a[4], b[4];
            for (int f = 0; f < 4; ++f) {
                a[f] = *reinterpret_cast<const bf16x8*>(
                    Alds + (wm * 64 + f * 16 + fr) * 64 + ks * 32 + kg * 8);
                b[f] = *reinterpret_cast<const bf16x8*>(
                    Blds + (wn * 64 + f * 16 + fr) * 64 + ks * 32 + kg * 8);
            }
            for (int fm = 0; fm < 4; ++fm)
                for (int fn = 0; fn < 4; ++fn)
                    acc[fm][fn] = __builtin_amdgcn_mfma_f32_16x16x32_bf16(
                        a[fm], b[fn], acc[fm][fn], 0, 0, 0);
        }
        __syncthreads();   // all reads done before next overwrite
    }

    // epilogue: x = dec + acc/sqrt(2048); C/D layout col=lane&15, row=(lane>>4)*4+j
    const float inv = 0.022097086912079612f;  // 1/sqrt(2048)
    const int col16 = lane & 15, rquad = lane >> 4;
    for (int fm = 0; fm < 4; ++fm)
        for (int fn = 0; fn < 4; ++fn)
            for (int j = 0; j < 4; ++j) {
                const int m = m0 + wm * 64 + fm * 16 + rquad * 4 + j;
                const int n = n0 + wn * 64 + fn * 16 + col16;
                const size_t o = (size_t)m * NCOLS + n;
                xout[o] = dec[o] + acc[fm][fn][j] * inv;
            }
}

// ---------------------------------------------------------------------------
// Kernel 4: LayerNorm over d=1024 per (m,b) row. 8192 blocks x 256 threads.
// ---------------------------------------------------------------------------
__global__ __launch_bounds__(256) void layernorm_rows(
    const float* __restrict__ x, const float* __restrict__ gamma,
    const float* __restrict__ beta, float* __restrict__ out)
{
    __shared__ float ps[4], pq[4];
    const int row = blockIdx.x;            // m*8 + b
    const int tid = threadIdx.x;
    const float* xr = x + (size_t)row * DMODEL;
    float4 v = *reinterpret_cast<const float4*>(xr + tid * 4);
    float s  = v.x + v.y + v.z + v.w;
    float sq = v.x * v.x + v.y * v.y + v.z * v.z + v.w * v.w;
    for (int off = 32; off > 0; off >>= 1) {
        s  += __shfl_down(s, off);
        sq += __shfl_down(sq, off);
    }
    const int wave = tid >> 6, lane = tid & 63;
    if (lane == 0) { ps[wave] = s; pq[wave] = sq; }
    __syncthreads();
    if (tid == 0) {
        float ts = ps[0] + ps[1] + ps[2] + ps[3];
        float tq = pq[0] + pq[1] + pq[2] + pq[3];
        float mu = ts * (1.0f / DMODEL);
        float var = tq * (1.0f / DMODEL) - mu * mu;
        ps[0] = mu;
        pq[0] = rsqrtf(var + 1e-5f);
    }
    __syncthreads();
    const float mu = ps[0], rs = pq[0];
    float4 g  = *reinterpret_cast<const float4*>(gamma + tid * 4);
    float4 be = *reinterpret_cast<const float4*>(beta + tid * 4);
    float4 o;
    o.x = g.x * (v.x - mu) * rs + be.x;
    o.y = g.y * (v.y - mu) * rs + be.y;
    o.z = g.z * (v.z - mu) * rs + be.z;
    o.w = g.w * (v.w - mu) * rs + be.w;
    *reinterpret_cast<float4*>(out + (size_t)row * DMODEL + tid * 4) = o;
}

extern "C" void kernel_launch(void* const* d_in, const int* in_sizes, int n_in,
                              void* d_out, int out_size, void* d_ws, size_t ws_size,
                              hipStream_t stream)
{
    const float* dec   = (const float*)d_in[0];
    const float* pos   = (const float*)d_in[1];
    const float* mems  = (const float*)d_in[2];
    const float* gamma = (const float*)d_in[3];
    const float* beta  = (const float*)d_in[4];
    const int*   addp  = (const int*)d_in[5];
    float* out = (float*)d_out;

    // ws layout: catT bf16 [8192][2048] (32MB) | W bf16 [1024][2048] (4MB) | x f32 (32MB)
    unsigned short* catT = (unsigned short*)d_ws;
    unsigned short* Wmat = catT + (size_t)NCOLS * KLEN;
    float* x = (float*)(Wmat + (size_t)QLEN * KLEN);

    prep_transpose<<<dim3(32, 16, 8), 256, 0, stream>>>(dec, pos, mems, addp, catT);
    fill_w<<<2048, 256, 0, stream>>>(Wmat);
    gemm_band<<<dim3(8, 64), 256, 0, stream>>>(Wmat, catT, dec, x);
    layernorm_rows<<<8192, 256, 0, stream>>>(x, gamma, beta, out);
}